// Round 8
// baseline (195.592 us; speedup 1.0000x reference)
//
#include <hip/hip_runtime.h>
#include <hip/hip_bf16.h>

#define THREADS 256
#define DIM 16

typedef __attribute__((ext_vector_type(8))) short bf16x8;
typedef __attribute__((ext_vector_type(16))) float f32x16;
typedef __attribute__((ext_vector_type(2))) float f32x2;

__device__ __forceinline__ float rawexp2(float a) { return __builtin_amdgcn_exp2f(a); }

// ---------------------------------------------------------------------------
// Prep: f32 -> bf16 RNE (truncation would bias each coordinate by -2^-9 and
// inject ~4.6e-6 bias into t1-t2). Outputs:
//   xbs/pbs = RNE(L2E * v~)             (A-operands, pre-scaled by log2 e)
//   pb      = v~                        (B-operand, particles only)
//   xn/pn   = -0.5*log2e*||v~||^2       (C-seed row terms, f32)
//   pfp     = exp2(-0.5*log2e*||p~||^2) (per-column factor, precomputed)
// Norms from the ROUNDED plain values; the t1 diagonal cancels to ~2^eta,
// eta ~ bf16 dot noise (random, ~1e-8 net on the output).
// ---------------------------------------------------------------------------
__global__ __launch_bounds__(THREADS) void prep_kernel(
    const float* __restrict__ x, int nx,
    const float* __restrict__ p, int np,
    short* __restrict__ xbs, float* __restrict__ xn,
    short* __restrict__ pbs, short* __restrict__ pb,
    float* __restrict__ pn, float* __restrict__ pfp)
{
    const float L2E  = 1.44269504088896340736f;
    const float HL2E = 0.72134752044448170368f;
    int i = blockIdx.x * THREADS + threadIdx.x;
    const float* src; short* ds; short* dp; float* dn; float* df;
    if (i < nx) {
        src = x + (size_t)i * DIM; ds = xbs + (size_t)i * DIM;
        dp = nullptr; dn = xn + i; df = nullptr;
    } else if (i < nx + np) {
        int j = i - nx;
        src = p + (size_t)j * DIM; ds = pbs + (size_t)j * DIM;
        dp = pb + (size_t)j * DIM; dn = pn + j; df = pfp + j;
    } else {
        return;
    }

    float nrm = 0.f;
    bf16x8 plo, phi, slo, shi;
#pragma unroll
    for (int k = 0; k < DIM; ++k) {
        unsigned u = __float_as_uint(src[k]);
        unsigned short r = (unsigned short)((u + 0x7FFFu + ((u >> 16) & 1u)) >> 16); // RNE
        float fr = __uint_as_float((unsigned)r << 16);
        nrm = fmaf(fr, fr, nrm);
        unsigned us = __float_as_uint(L2E * fr);
        unsigned short rs = (unsigned short)((us + 0x7FFFu + ((us >> 16) & 1u)) >> 16); // RNE
        if (k < 8) { plo[k] = (short)r; slo[k] = (short)rs; }
        else       { phi[k - 8] = (short)r; shi[k - 8] = (short)rs; }
    }
    *(bf16x8*)ds = slo; *((bf16x8*)ds + 1) = shi;
    if (dp) { *(bf16x8*)dp = plo; *((bf16x8*)dp + 1) = phi; }
    float ns = -HL2E * nrm;
    *dn = ns;
    if (df) *df = rawexp2(ns);
}

// Consume one MFMA result: 16 raw v_exp_f32 + 8 v_pk_fma_f32.
__device__ __forceinline__ void consume_tile(const f32x16& d, float f, f32x2& acc)
{
    f32x2 pf2 = {f, f};
#pragma unroll
    for (int r = 0; r < 8; ++r) {
        f32x2 e = { rawexp2(d[2 * r]), rawexp2(d[2 * r + 1]) };
        acc = e * pf2 + acc;
    }
}

// ---------------------------------------------------------------------------
// TWO row-tiles (64 rows, one A-pair) x NT col-tiles, fully unrolled
// (NT compile-time): one b-load + one pf-load feed TWO MFMAs -> per-MFMA glue
// halves, loop overhead vanishes, addresses strength-reduce.
// MFMA 32x32x16 bf16, A pre-scaled by L2E, C seeded with -HL2E*||row||^2:
//   d[r] = L2E*dot - HL2E*||row||^2 ; e = 2^d ; acc = pk_fma(e, pf_col, acc)
//   A/B frag: lane l holds point (l&31), k = (l>>5)*8 + i
//   D:        lane l, reg r -> row = (r&3) + 8*(r>>2) + 4*(l>>5), col = l&31
// All 16 d-elements of a lane share col (l&31) -> one pf per lane per tile.
// e = 2^d can reach ~2^72 on the t1 diagonal; no overflow, e*pf <= ~1.
// bq/fq: 2-slot circular buffer, indices compile-time after full unroll.
// Separate accA/accB keep each row-tile's f32 chain identical to R7's order.
// ---------------------------------------------------------------------------
template<int NT>
__device__ __forceinline__ void pair_phase(
    const short* __restrict__ rowsb, const float* __restrict__ rown,
    const short* __restrict__ colsb, const float* __restrict__ colpf,
    int row0, int ct0, int l31, int half,
    float& outA, float& outB)
{
    bf16x8 a0 = *(const bf16x8*)(rowsb + (size_t)(row0 + l31) * DIM + half * 8);
    bf16x8 a1 = *(const bf16x8*)(rowsb + (size_t)(row0 + 32 + l31) * DIM + half * 8);

    f32x16 c0, c1;
#pragma unroll
    for (int r = 0; r < 16; ++r) {
        int rrow = (r & 3) + 8 * (r >> 2) + 4 * half;
        c0[r] = rown[row0 + rrow];           // -HL2E*||row||^2 (prescaled)
        c1[r] = rown[row0 + 32 + rrow];
    }

    const short* bptr = colsb + ((size_t)ct0 * 32 + l31) * DIM + half * 8;
    const float* fptr = colpf + ct0 * 32 + l31;
    const size_t bstride = (size_t)32 * DIM;

    bf16x8 bq[2]; float fq[2];
    bq[0] = *(const bf16x8*)bptr;            fq[0] = fptr[0];
    bq[1] = *(const bf16x8*)(bptr + bstride); fq[1] = fptr[32];

    f32x2 accA = {0.f, 0.f}, accB = {0.f, 0.f};

#pragma unroll
    for (int t = 0; t < NT; ++t) {
        bf16x8 bcur = bq[t & 1];
        float  pf   = fq[t & 1];
        if (t + 2 < NT) {                     // compile-time predicate
            bq[t & 1] = *(const bf16x8*)(bptr + (size_t)(t + 2) * bstride);
            fq[t & 1] = fptr[(t + 2) * 32];
        }
        f32x16 d0 = __builtin_amdgcn_mfma_f32_32x32x16_bf16(a0, bcur, c0, 0, 0, 0);
        f32x16 d1 = __builtin_amdgcn_mfma_f32_32x32x16_bf16(a1, bcur, c1, 0, 0, 0);
        consume_tile(d0, pf, accA);           // d1's MFMA in flight meanwhile
        consume_tile(d1, pf, accB);
    }
    outA = accA.x + accA.y;
    outB = accB.x + accB.y;
}

// ---------------------------------------------------------------------------
// Fused t1 + t2: 4096 waves (1024 blocks, all resident at 4 blocks/CU).
// Each wave: one 64-row pair x NT1 t1 col-tiles + one pair x NT2 t2 col-tiles.
//   t1: 128 row-pairs x 32 chunks of NT1=8  -> 4096 assignments
//   t2: 512 row-pairs x 8  chunks of NT2=32 -> 4096 assignments
// ---------------------------------------------------------------------------
__global__ __launch_bounds__(THREADS) void gram_fused_kernel(
    const short* __restrict__ xbs, const float* __restrict__ xn,
    const short* __restrict__ pbs, const short* __restrict__ pb,
    const float* __restrict__ pn, const float* __restrict__ pfp,
    double sc1, double sc2,
    double* __restrict__ partials)
{
    const int lane = threadIdx.x & 63;
    const int wv   = threadIdx.x >> 6;
    const int l31  = lane & 31;
    const int half = lane >> 5;
    const int w    = blockIdx.x * (THREADS / 64) + wv;

    // t1: P x P  (rows = scaled particles, cols = plain particles)
    float a1s, b1s;
    {
        const int rp = w & 127;              // 128 row-pairs
        const int c0 = (w >> 7) * 8;         // 32 chunks x 8 tiles
        pair_phase<8>(pbs, pn, pb, pfp, rp * 64, c0, l31, half, a1s, b1s);
    }

    // t2: X x P
    float a2s, b2s;
    {
        const int rp = w & 511;              // 512 row-pairs
        const int c0 = (w >> 9) * 32;        // 8 chunks x 32 tiles
        pair_phase<32>(xbs, xn, pb, pfp, rp * 64, c0, l31, half, a2s, b2s);
    }

    double v = ((double)a1s + (double)b1s) * sc1
             - ((double)a2s + (double)b2s) * sc2;
#pragma unroll
    for (int off = 32; off > 0; off >>= 1) v += __shfl_down(v, off);

    __shared__ double sred[THREADS / 64];
    if (lane == 0) sred[wv] = v;
    __syncthreads();
    if (threadIdx.x == 0) {
        double tot = 0.0;
#pragma unroll
        for (int q = 0; q < THREADS / 64; ++q) tot += sred[q];
        partials[blockIdx.x] = tot;
    }
}

__global__ __launch_bounds__(THREADS) void finalize_kernel(
    const double* __restrict__ partials, int n, float* __restrict__ out)
{
    double v = 0.0;
    for (int i = threadIdx.x; i < n; i += THREADS) v += partials[i];
#pragma unroll
    for (int off = 32; off > 0; off >>= 1) v += __shfl_down(v, off);

    __shared__ double sred[THREADS / 64];
    const int lane = threadIdx.x & 63;
    const int wid = threadIdx.x >> 6;
    if (lane == 0) sred[wid] = v;
    __syncthreads();
    if (threadIdx.x == 0) {
        double tot = 0.0;
#pragma unroll
        for (int q = 0; q < THREADS / 64; ++q) tot += sred[q];
        out[0] = (float)tot;
    }
}

extern "C" void kernel_launch(void* const* d_in, const int* in_sizes, int n_in,
                              void* d_out, int out_size, void* d_ws, size_t ws_size,
                              hipStream_t stream) {
    const float* x = (const float*)d_in[0];         // [NX, 16]
    const float* particles = (const float*)d_in[1]; // [NP, 16]
    float* out = (float*)d_out;

    const int NX = in_sizes[0] / DIM;  // 32768
    const int NP = in_sizes[1] / DIM;  // 8192

    const int NBLOCKS = 1024;          // 4096 waves, all resident

    // ---- workspace layout (16B-aligned offsets) ----
    char* ws = (char*)d_ws;
    double* partials = (double*)ws;                  //    8 KB @ 0
    float*  xn  = (float*)(ws + 16384);              //  128 KB
    float*  pn  = (float*)(ws + 147456);             //   32 KB
    float*  pfp = (float*)(ws + 180224);             //   32 KB
    short*  xbs = (short*)(ws + 212992);             //    1 MB (scaled x)
    short*  pbs = (short*)(ws + 1261568);            //  256 KB (scaled p)
    short*  pb  = (short*)(ws + 1523712);            //  256 KB (plain p)

    // 1) convert + norms + column factors
    const int nprep = (NX + NP + THREADS - 1) / THREADS;
    prep_kernel<<<nprep, THREADS, 0, stream>>>(x, NX, particles, NP,
                                               xbs, xn, pbs, pb, pn, pfp);

    // 2) fused gram sums (scales applied per-wave in f64)
    gram_fused_kernel<<<NBLOCKS, THREADS, 0, stream>>>(
        xbs, xn, pbs, pb, pn, pfp,
        1.0 / ((double)NP * (double)NP),
        2.0 / ((double)NX * (double)NP),
        partials);

    // 3) combine
    finalize_kernel<<<1, THREADS, 0, stream>>>(partials, NBLOCKS, out);
}

// Round 9
// 108.094 us; speedup vs baseline: 1.8095x; 1.8095x over previous
//
#include <hip/hip_runtime.h>
#include <hip/hip_bf16.h>

#define THREADS 256
#define DIM 16

typedef __attribute__((ext_vector_type(8))) short bf16x8;
typedef __attribute__((ext_vector_type(16))) float f32x16;
typedef __attribute__((ext_vector_type(2))) float f32x2;

__device__ __forceinline__ float rawexp2(float a) { return __builtin_amdgcn_exp2f(a); }

// ---------------------------------------------------------------------------
// Prep: f32 -> bf16 RNE (truncation would bias each coordinate by -2^-9 and
// inject ~4.6e-6 bias into t1-t2). Outputs:
//   xbs/pbs = RNE(L2E * v~)             (A-operands, pre-scaled by log2 e)
//   pb      = v~                        (B-operand, particles only)
//   xn/pn   = -0.5*log2e*||v~||^2       (C-seed row terms, f32)
//   pfp     = exp2(-0.5*log2e*||p~||^2) (per-column factor, precomputed)
// Norms from the ROUNDED plain values; the t1 diagonal cancels to ~2^eta,
// eta ~ bf16 dot noise (random, ~1e-8 net on the output).
// ---------------------------------------------------------------------------
__global__ __launch_bounds__(THREADS) void prep_kernel(
    const float* __restrict__ x, int nx,
    const float* __restrict__ p, int np,
    short* __restrict__ xbs, float* __restrict__ xn,
    short* __restrict__ pbs, short* __restrict__ pb,
    float* __restrict__ pn, float* __restrict__ pfp)
{
    const float L2E  = 1.44269504088896340736f;
    const float HL2E = 0.72134752044448170368f;
    int i = blockIdx.x * THREADS + threadIdx.x;
    const float* src; short* ds; short* dp; float* dn; float* df;
    if (i < nx) {
        src = x + (size_t)i * DIM; ds = xbs + (size_t)i * DIM;
        dp = nullptr; dn = xn + i; df = nullptr;
    } else if (i < nx + np) {
        int j = i - nx;
        src = p + (size_t)j * DIM; ds = pbs + (size_t)j * DIM;
        dp = pb + (size_t)j * DIM; dn = pn + j; df = pfp + j;
    } else {
        return;
    }

    float nrm = 0.f;
    bf16x8 plo, phi, slo, shi;
#pragma unroll
    for (int k = 0; k < DIM; ++k) {
        unsigned u = __float_as_uint(src[k]);
        unsigned short r = (unsigned short)((u + 0x7FFFu + ((u >> 16) & 1u)) >> 16); // RNE
        float fr = __uint_as_float((unsigned)r << 16);
        nrm = fmaf(fr, fr, nrm);
        unsigned us = __float_as_uint(L2E * fr);
        unsigned short rs = (unsigned short)((us + 0x7FFFu + ((us >> 16) & 1u)) >> 16); // RNE
        if (k < 8) { plo[k] = (short)r; slo[k] = (short)rs; }
        else       { phi[k - 8] = (short)r; shi[k - 8] = (short)rs; }
    }
    *(bf16x8*)ds = slo; *((bf16x8*)ds + 1) = shi;
    if (dp) { *(bf16x8*)dp = plo; *((bf16x8*)dp + 1) = phi; }
    float ns = -HL2E * nrm;
    *dn = ns;
    if (df) *df = rawexp2(ns);
}

// Consume one MFMA result: 16 raw v_exp_f32 + 8 v_pk_fma_f32.
__device__ __forceinline__ void consume_tile(const f32x16& d, float f, f32x2& acc)
{
    f32x2 pf2 = {f, f};
#pragma unroll
    for (int r = 0; r < 8; ++r) {
        f32x2 e = { rawexp2(d[2 * r]), rawexp2(d[2 * r + 1]) };
        acc = e * pf2 + acc;
    }
}

// ---------------------------------------------------------------------------
// TWO row-tiles (64 rows, one A-pair) x ntiles col-tiles, RUNTIME loop with
// #pragma unroll 1 (R8 lesson: full unroll -> 256 VGPR + scratch spills).
// Each B-fragment load feeds TWO MFMAs (A-side reuse): per-tile glue halves.
// Named ping-pong (dA*, dB*) over col-tile pairs, one-pair prefetch distance.
// MFMA 32x32x16 bf16, A pre-scaled by L2E, C seeded with -HL2E*||row||^2:
//   d[r] = L2E*dot - HL2E*||row||^2 ; e = 2^d ; acc = pk_fma(e, pf_col, acc)
//   A/B frag: lane l holds point (l&31), k = (l>>5)*8 + i
//   D:        lane l, reg r -> row = (r&3) + 8*(r>>2) + 4*(l>>5), col = l&31
// All 16 d-elements of a lane share col (l&31) -> one pf per lane per tile.
// e = 2^d can reach ~2^72 on the t1 diagonal; no overflow, e*pf <= ~1.
// accA = row-tile row0, accB = row-tile row0+32 (per-row-tile chain order
// identical to R7's proven accumulation). ntiles even, >= 4.
// ---------------------------------------------------------------------------
__device__ __forceinline__ void pair_phase(
    const short* __restrict__ rowsb, const float* __restrict__ rown,
    const short* __restrict__ colsb, const float* __restrict__ colpf,
    int row0, int ct0, int ntiles, int l31, int half,
    float& outA, float& outB)
{
    bf16x8 a0 = *(const bf16x8*)(rowsb + (size_t)(row0 + l31) * DIM + half * 8);
    bf16x8 a1 = *(const bf16x8*)(rowsb + (size_t)(row0 + 32 + l31) * DIM + half * 8);

    f32x16 c0, c1;
#pragma unroll
    for (int r = 0; r < 16; ++r) {
        int rrow = (r & 3) + 8 * (r >> 2) + 4 * half;
        c0[r] = rown[row0 + rrow];           // -HL2E*||row||^2 (prescaled)
        c1[r] = rown[row0 + 32 + rrow];
    }

    const short* bptr = colsb + ((size_t)ct0 * 32 + l31) * DIM + half * 8;
    const float* fptr = colpf + ct0 * 32 + l31;
    const size_t bstride = (size_t)32 * DIM;

    // prologue: tiles 0 and 1
    bf16x8 b0 = *(const bf16x8*)bptr;
    float  fA = fptr[0];
    f32x16 dA0 = __builtin_amdgcn_mfma_f32_32x32x16_bf16(a0, b0, c0, 0, 0, 0);
    f32x16 dA1 = __builtin_amdgcn_mfma_f32_32x32x16_bf16(a1, b0, c1, 0, 0, 0);
    bf16x8 b1 = *(const bf16x8*)(bptr + bstride);
    float  fB = fptr[32];
    f32x16 dB0 = __builtin_amdgcn_mfma_f32_32x32x16_bf16(a0, b1, c0, 0, 0, 0);
    f32x16 dB1 = __builtin_amdgcn_mfma_f32_32x32x16_bf16(a1, b1, c1, 0, 0, 0);

    f32x2 accA = {0.f, 0.f}, accB = {0.f, 0.f};

#pragma unroll 1
    for (int t = 0; t + 2 < ntiles; t += 2) {
        bf16x8 bn0 = *(const bf16x8*)(bptr + (size_t)(t + 2) * bstride);
        float  fn0 = fptr[(t + 2) * 32];
        consume_tile(dA0, fA, accA);          // dB MFMAs (prev iter) in flight
        consume_tile(dA1, fA, accB);
        dA0 = __builtin_amdgcn_mfma_f32_32x32x16_bf16(a0, bn0, c0, 0, 0, 0);
        dA1 = __builtin_amdgcn_mfma_f32_32x32x16_bf16(a1, bn0, c1, 0, 0, 0);
        fA = fn0;

        bf16x8 bn1 = *(const bf16x8*)(bptr + (size_t)(t + 3) * bstride);
        float  fn1 = fptr[(t + 3) * 32];
        consume_tile(dB0, fB, accA);
        consume_tile(dB1, fB, accB);
        dB0 = __builtin_amdgcn_mfma_f32_32x32x16_bf16(a0, bn1, c0, 0, 0, 0);
        dB1 = __builtin_amdgcn_mfma_f32_32x32x16_bf16(a1, bn1, c1, 0, 0, 0);
        fB = fn1;
    }
    consume_tile(dA0, fA, accA);
    consume_tile(dA1, fA, accB);
    consume_tile(dB0, fB, accA);
    consume_tile(dB1, fB, accB);
    outA = accA.x + accA.y;
    outB = accB.x + accB.y;
}

// ---------------------------------------------------------------------------
// Fused t1 + t2: 4096 waves (1024 blocks). Each wave: one 64-row pair x 8
// t1 col-tiles + one 64-row pair x 32 t2 col-tiles.
//   t1: 128 row-pairs x 32 chunks of 8  -> 4096 assignments
//   t2: 512 row-pairs x 8  chunks of 32 -> 4096 assignments
// __launch_bounds__(256,3): VGPR cap 170 (kernel needs ~130-150) -> NO spill
// possible (R8 lesson). R5-R7 showed duration is occupancy-invariant at
// >=3 waves/SIMD, so 3-wave residency is sufficient.
// ---------------------------------------------------------------------------
__global__ __launch_bounds__(THREADS, 3) void gram_fused_kernel(
    const short* __restrict__ xbs, const float* __restrict__ xn,
    const short* __restrict__ pbs, const short* __restrict__ pb,
    const float* __restrict__ pn, const float* __restrict__ pfp,
    double sc1, double sc2,
    double* __restrict__ partials)
{
    const int lane = threadIdx.x & 63;
    const int wv   = threadIdx.x >> 6;
    const int l31  = lane & 31;
    const int half = lane >> 5;
    const int w    = blockIdx.x * (THREADS / 64) + wv;

    // t1: P x P  (rows = scaled particles, cols = plain particles)
    float a1s, b1s;
    {
        const int rp = w & 127;              // 128 row-pairs
        const int c0 = (w >> 7) * 8;         // 32 chunks x 8 tiles
        pair_phase(pbs, pn, pb, pfp, rp * 64, c0, 8, l31, half, a1s, b1s);
    }

    // t2: X x P
    float a2s, b2s;
    {
        const int rp = w & 511;              // 512 row-pairs
        const int c0 = (w >> 9) * 32;        // 8 chunks x 32 tiles
        pair_phase(xbs, xn, pb, pfp, rp * 64, c0, 32, l31, half, a2s, b2s);
    }

    double v = ((double)a1s + (double)b1s) * sc1
             - ((double)a2s + (double)b2s) * sc2;
#pragma unroll
    for (int off = 32; off > 0; off >>= 1) v += __shfl_down(v, off);

    __shared__ double sred[THREADS / 64];
    if (lane == 0) sred[wv] = v;
    __syncthreads();
    if (threadIdx.x == 0) {
        double tot = 0.0;
#pragma unroll
        for (int q = 0; q < THREADS / 64; ++q) tot += sred[q];
        partials[blockIdx.x] = tot;
    }
}

__global__ __launch_bounds__(THREADS) void finalize_kernel(
    const double* __restrict__ partials, int n, float* __restrict__ out)
{
    double v = 0.0;
    for (int i = threadIdx.x; i < n; i += THREADS) v += partials[i];
#pragma unroll
    for (int off = 32; off > 0; off >>= 1) v += __shfl_down(v, off);

    __shared__ double sred[THREADS / 64];
    const int lane = threadIdx.x & 63;
    const int wid = threadIdx.x >> 6;
    if (lane == 0) sred[wid] = v;
    __syncthreads();
    if (threadIdx.x == 0) {
        double tot = 0.0;
#pragma unroll
        for (int q = 0; q < THREADS / 64; ++q) tot += sred[q];
        out[0] = (float)tot;
    }
}

extern "C" void kernel_launch(void* const* d_in, const int* in_sizes, int n_in,
                              void* d_out, int out_size, void* d_ws, size_t ws_size,
                              hipStream_t stream) {
    const float* x = (const float*)d_in[0];         // [NX, 16]
    const float* particles = (const float*)d_in[1]; // [NP, 16]
    float* out = (float*)d_out;

    const int NX = in_sizes[0] / DIM;  // 32768
    const int NP = in_sizes[1] / DIM;  // 8192

    const int NBLOCKS = 1024;          // 4096 waves

    // ---- workspace layout (16B-aligned offsets) ----
    char* ws = (char*)d_ws;
    double* partials = (double*)ws;                  //    8 KB @ 0
    float*  xn  = (float*)(ws + 16384);              //  128 KB
    float*  pn  = (float*)(ws + 147456);             //   32 KB
    float*  pfp = (float*)(ws + 180224);             //   32 KB
    short*  xbs = (short*)(ws + 212992);             //    1 MB (scaled x)
    short*  pbs = (short*)(ws + 1261568);            //  256 KB (scaled p)
    short*  pb  = (short*)(ws + 1523712);            //  256 KB (plain p)

    // 1) convert + norms + column factors
    const int nprep = (NX + NP + THREADS - 1) / THREADS;
    prep_kernel<<<nprep, THREADS, 0, stream>>>(x, NX, particles, NP,
                                               xbs, xn, pbs, pb, pn, pfp);

    // 2) fused gram sums (scales applied per-wave in f64)
    gram_fused_kernel<<<NBLOCKS, THREADS, 0, stream>>>(
        xbs, xn, pbs, pb, pn, pfp,
        1.0 / ((double)NP * (double)NP),
        2.0 / ((double)NX * (double)NP),
        partials);

    // 3) combine
    finalize_kernel<<<1, THREADS, 0, stream>>>(partials, NBLOCKS, out);
}

// Round 10
// 49.646 us; speedup vs baseline: 3.9398x; 2.1773x over previous
//
#include <hip/hip_runtime.h>
#include <hip/hip_bf16.h>

#define THREADS 256
#define DIM 16

typedef __attribute__((ext_vector_type(8))) short bf16x8;
typedef __attribute__((ext_vector_type(16))) float f32x16;
typedef __attribute__((ext_vector_type(2))) float f32x2;

__device__ __forceinline__ float rawexp2(float a) { return __builtin_amdgcn_exp2f(a); }

// ---------------------------------------------------------------------------
// Prep: f32 -> bf16 RNE (truncation would bias each coordinate by -2^-9 and
// inject ~4.6e-6 bias into t1-t2). Outputs:
//   xbs/pbs = RNE(L2E * v~)             (A-operands, pre-scaled by log2 e)
//   pb      = v~                        (B-operand, particles only)
//   xn/pn   = -0.5*log2e*||v~||^2       (C-seed row terms, f32)
//   pfp     = exp2(-0.5*log2e*||p~||^2) (per-column factor, precomputed)
// Norms from the ROUNDED plain values; the t1 diagonal cancels to ~2^eta,
// eta ~ bf16 dot noise (random, ~1e-8 net on the output).
// ---------------------------------------------------------------------------
__global__ __launch_bounds__(THREADS) void prep_kernel(
    const float* __restrict__ x, int nx,
    const float* __restrict__ p, int np,
    short* __restrict__ xbs, float* __restrict__ xn,
    short* __restrict__ pbs, short* __restrict__ pb,
    float* __restrict__ pn, float* __restrict__ pfp)
{
    const float L2E  = 1.44269504088896340736f;
    const float HL2E = 0.72134752044448170368f;
    int i = blockIdx.x * THREADS + threadIdx.x;
    const float* src; short* ds; short* dp; float* dn; float* df;
    if (i < nx) {
        src = x + (size_t)i * DIM; ds = xbs + (size_t)i * DIM;
        dp = nullptr; dn = xn + i; df = nullptr;
    } else if (i < nx + np) {
        int j = i - nx;
        src = p + (size_t)j * DIM; ds = pbs + (size_t)j * DIM;
        dp = pb + (size_t)j * DIM; dn = pn + j; df = pfp + j;
    } else {
        return;
    }

    float nrm = 0.f;
    bf16x8 plo, phi, slo, shi;
#pragma unroll
    for (int k = 0; k < DIM; ++k) {
        unsigned u = __float_as_uint(src[k]);
        unsigned short r = (unsigned short)((u + 0x7FFFu + ((u >> 16) & 1u)) >> 16); // RNE
        float fr = __uint_as_float((unsigned)r << 16);
        nrm = fmaf(fr, fr, nrm);
        unsigned us = __float_as_uint(L2E * fr);
        unsigned short rs = (unsigned short)((us + 0x7FFFu + ((us >> 16) & 1u)) >> 16); // RNE
        if (k < 8) { plo[k] = (short)r; slo[k] = (short)rs; }
        else       { phi[k - 8] = (short)r; shi[k - 8] = (short)rs; }
    }
    *(bf16x8*)ds = slo; *((bf16x8*)ds + 1) = shi;
    if (dp) { *(bf16x8*)dp = plo; *((bf16x8*)dp + 1) = phi; }
    float ns = -HL2E * nrm;
    *dn = ns;
    if (df) *df = rawexp2(ns);
}

// ---------------------------------------------------------------------------
// Consume one MFMA result, PHASE-SEPARATED (R10 change):
//   phase 1: 16 raw v_exp_f32 back-to-back into e[] (no consumer between
//            exps -> the trans pipe streams; no exp->fma dependency stall)
//   phase 2: pairwise pk_add tree (7 ops) + one pk_fma with pf
// Same packed-op count as R7's interleaved form; only dependencies change.
// e[] indices are compile-time constants after unroll (rule #20 safe).
// ---------------------------------------------------------------------------
__device__ __forceinline__ void consume_tile(const f32x16& d, float f, f32x2& acc)
{
    f32x2 e0 = { rawexp2(d[0]),  rawexp2(d[1])  };
    f32x2 e1 = { rawexp2(d[2]),  rawexp2(d[3])  };
    f32x2 e2 = { rawexp2(d[4]),  rawexp2(d[5])  };
    f32x2 e3 = { rawexp2(d[6]),  rawexp2(d[7])  };
    f32x2 e4 = { rawexp2(d[8]),  rawexp2(d[9])  };
    f32x2 e5 = { rawexp2(d[10]), rawexp2(d[11]) };
    f32x2 e6 = { rawexp2(d[12]), rawexp2(d[13]) };
    f32x2 e7 = { rawexp2(d[14]), rawexp2(d[15]) };

    f32x2 s0 = e0 + e1;
    f32x2 s1 = e2 + e3;
    f32x2 s2 = e4 + e5;
    f32x2 s3 = e6 + e7;
    f32x2 u0 = s0 + s1;
    f32x2 u1 = s2 + s3;
    f32x2 t  = u0 + u1;
    f32x2 pf2 = {f, f};
    acc = t * pf2 + acc;
}

// ---------------------------------------------------------------------------
// One 32-row-tile x ntiles 32-col-tiles gram partial sum.
// Ping-pong pipeline (d0/d1, static names, <=2 live f32x16 results — R8/R9
// lesson: 4 live results force AGPR/scratch shuffling):
//   per 2 tiles: prefetch next-pair b/f, consume d0, remfma d0,
//                consume d1, remfma d1.
// MFMA 32x32x16 bf16, A pre-scaled by L2E, C seeded with -HL2E*||row||^2:
//   d[r] = L2E*dot - HL2E*||row||^2 ; e = 2^d ; acc += pf_col * sum(e)
//   A/B frag: lane l holds point (l&31), k = (l>>5)*8 + i
//   D:        lane l, reg r -> row = (r&3) + 8*(r>>2) + 4*(l>>5), col = l&31
// All 16 d-elements of a lane share col (l&31) -> one pf per lane per tile.
// e = 2^d can reach ~2^72 on the t1 diagonal; no overflow, e*pf <= ~1.
// ntiles must be even and >= 2 (16 and 64 here).
// ---------------------------------------------------------------------------
__device__ __forceinline__ float gram_phase(
    const short* __restrict__ rowsb, const float* __restrict__ rown,
    const short* __restrict__ colsb, const float* __restrict__ colpf,
    int row0, int ct0, int ntiles, int l31, int half)
{
    bf16x8 afrag = *(const bf16x8*)(rowsb + (size_t)(row0 + l31) * DIM + half * 8);

    f32x16 cseed;
#pragma unroll
    for (int r = 0; r < 16; ++r) {
        int rrow = (r & 3) + 8 * (r >> 2) + 4 * half;
        cseed[r] = rown[row0 + rrow];      // = -HL2E*||row||^2 (prescaled)
    }

    const short* bptr = colsb + ((size_t)ct0 * 32 + l31) * DIM + half * 8;
    const float* fptr = colpf + ct0 * 32 + l31;
    const size_t bstride = (size_t)32 * DIM;

    bf16x8 b0 = *(const bf16x8*)bptr;
    bf16x8 b1 = *(const bf16x8*)(bptr + bstride);
    float  f0 = fptr[0];
    float  f1 = fptr[32];

    f32x16 d0 = __builtin_amdgcn_mfma_f32_32x32x16_bf16(afrag, b0, cseed, 0, 0, 0);
    f32x16 d1 = __builtin_amdgcn_mfma_f32_32x32x16_bf16(afrag, b1, cseed, 0, 0, 0);

    f32x2 acc = {0.f, 0.f};

#pragma unroll 1
    for (int t = 0; t + 2 < ntiles; t += 2) {
        // prefetch next pair before consuming current pair (~250cy lead)
        bf16x8 bn0 = *(const bf16x8*)(bptr + (size_t)(t + 2) * bstride);
        float  fn0 = fptr[(t + 2) * 32];
        bf16x8 bn1 = *(const bf16x8*)(bptr + (size_t)(t + 3) * bstride);
        float  fn1 = fptr[(t + 3) * 32];

        consume_tile(d0, f0, acc);
        d0 = __builtin_amdgcn_mfma_f32_32x32x16_bf16(afrag, bn0, cseed, 0, 0, 0);
        consume_tile(d1, f1, acc);
        d1 = __builtin_amdgcn_mfma_f32_32x32x16_bf16(afrag, bn1, cseed, 0, 0, 0);

        f0 = fn0; f1 = fn1;
    }
    consume_tile(d0, f0, acc);
    consume_tile(d1, f1, acc);
    return acc.x + acc.y;
}

// ---------------------------------------------------------------------------
// Fused t1 + t2: 4096 waves (1024 blocks, 4 blocks/CU, all resident).
// Each wave: exactly n1 t1-tiles + n2 t2-tiles. Perfect static balance.
// ---------------------------------------------------------------------------
__global__ __launch_bounds__(THREADS) void gram_fused_kernel(
    const short* __restrict__ xbs, const float* __restrict__ xn,
    const short* __restrict__ pbs, const short* __restrict__ pb,
    const float* __restrict__ pn, const float* __restrict__ pfp,
    int nrt_p, int n1,
    int nrt_x, int n2,
    double sc1, double sc2,
    double* __restrict__ partials)
{
    const int lane = threadIdx.x & 63;
    const int wv   = threadIdx.x >> 6;
    const int l31  = lane & 31;
    const int half = lane >> 5;
    const int w    = blockIdx.x * (THREADS / 64) + wv;

    // t1: P x P  (rows = scaled particles, cols = plain particles)
    const int rt1 = w & (nrt_p - 1);
    const int c10 = (w / nrt_p) * n1;
    float acc1 = gram_phase(pbs, pn, pb, pfp, rt1 * 32, c10, n1, l31, half);

    // t2: X x P
    const int rt2 = w & (nrt_x - 1);
    const int c20 = (w / nrt_x) * n2;
    float acc2 = gram_phase(xbs, xn, pb, pfp, rt2 * 32, c20, n2, l31, half);

    double v = (double)acc1 * sc1 - (double)acc2 * sc2;
#pragma unroll
    for (int off = 32; off > 0; off >>= 1) v += __shfl_down(v, off);

    __shared__ double sred[THREADS / 64];
    if (lane == 0) sred[wv] = v;
    __syncthreads();
    if (threadIdx.x == 0) {
        double tot = 0.0;
#pragma unroll
        for (int q = 0; q < THREADS / 64; ++q) tot += sred[q];
        partials[blockIdx.x] = tot;
    }
}

__global__ __launch_bounds__(THREADS) void finalize_kernel(
    const double* __restrict__ partials, int n, float* __restrict__ out)
{
    double v = 0.0;
    for (int i = threadIdx.x; i < n; i += THREADS) v += partials[i];
#pragma unroll
    for (int off = 32; off > 0; off >>= 1) v += __shfl_down(v, off);

    __shared__ double sred[THREADS / 64];
    const int lane = threadIdx.x & 63;
    const int wid = threadIdx.x >> 6;
    if (lane == 0) sred[wid] = v;
    __syncthreads();
    if (threadIdx.x == 0) {
        double tot = 0.0;
#pragma unroll
        for (int q = 0; q < THREADS / 64; ++q) tot += sred[q];
        out[0] = (float)tot;
    }
}

extern "C" void kernel_launch(void* const* d_in, const int* in_sizes, int n_in,
                              void* d_out, int out_size, void* d_ws, size_t ws_size,
                              hipStream_t stream) {
    const float* x = (const float*)d_in[0];         // [NX, 16]
    const float* particles = (const float*)d_in[1]; // [NP, 16]
    float* out = (float*)d_out;

    const int NX = in_sizes[0] / DIM;  // 32768
    const int NP = in_sizes[1] / DIM;  // 8192

    const int nrt_x = NX / 32;         // 1024 (pow2)
    const int nrt_p = NP / 32;         // 256  (pow2)

    const int NBLOCKS = 1024;          // 4096 waves, 4 blocks/CU, all resident
    const int WAVES = NBLOCKS * (THREADS / 64);
    const int n1 = (nrt_p * nrt_p) / WAVES;  // 16 (even)
    const int n2 = (nrt_x * nrt_p) / WAVES;  // 64 (even)

    // ---- workspace layout (16B-aligned offsets) ----
    char* ws = (char*)d_ws;
    double* partials = (double*)ws;                  //    8 KB @ 0
    float*  xn  = (float*)(ws + 16384);              //  128 KB
    float*  pn  = (float*)(ws + 147456);             //   32 KB
    float*  pfp = (float*)(ws + 180224);             //   32 KB
    short*  xbs = (short*)(ws + 212992);             //    1 MB (scaled x)
    short*  pbs = (short*)(ws + 1261568);            //  256 KB (scaled p)
    short*  pb  = (short*)(ws + 1523712);            //  256 KB (plain p)

    // 1) convert + norms + column factors
    const int nprep = (NX + NP + THREADS - 1) / THREADS;
    prep_kernel<<<nprep, THREADS, 0, stream>>>(x, NX, particles, NP,
                                               xbs, xn, pbs, pb, pn, pfp);

    // 2) fused gram sums (scales applied per-wave in f64)
    gram_fused_kernel<<<NBLOCKS, THREADS, 0, stream>>>(
        xbs, xn, pbs, pb, pn, pfp,
        nrt_p, n1, nrt_x, n2,
        1.0 / ((double)NP * (double)NP),
        2.0 / ((double)NX * (double)NP),
        partials);

    // 3) combine
    finalize_kernel<<<1, THREADS, 0, stream>>>(partials, NBLOCKS, out);
}